// Round 8
// baseline (61822.223 us; speedup 1.0000x reference)
//
#include <hip/hip_runtime.h>
#include <hip/hip_cooperative_groups.h>
#include <cstdint>
#include <cstddef>

namespace cg = cooperative_groups;

typedef _Float16 f16;
typedef _Float16 h2v __attribute__((ext_vector_type(2)));
typedef _Float16 h4v __attribute__((ext_vector_type(4)));
typedef _Float16 h8v __attribute__((ext_vector_type(8)));

static constexpr int BATCH = 128;
static constexpr int TSTEPS = 512;
static constexpr int NT = 256;
static constexpr int CK = 48;          // k-rows per staged chunk (12 KB f16)
static constexpr int RING = 4;         // h ring depth per layer

// ---------------- workspace layout (byte offsets) ----------------
static constexpr size_t B_XT  = 0;                               // f16 [512][64][128]
static constexpr size_t B_H1  = B_XT + 512ull * 64 * 128 * 2;    // f16 ring [4][H][128]
static constexpr size_t B_H2  = B_H1 + (size_t)RING * 640 * 128 * 2;
static constexpr size_t B_H3  = B_H2 + (size_t)RING * 400 * 128 * 2;
static constexpr size_t B_H4  = B_H3 + (size_t)RING * 256 * 128 * 2;
static constexpr size_t B_HEND= B_H4 + (size_t)RING * 256 * 128 * 2;
static constexpr size_t B_PK1 = B_HEND;                          // f32 packs
static constexpr size_t B_PK2 = B_PK1 + 640ull * 704  * 4 * 4;
static constexpr size_t B_PK3 = B_PK2 + 400ull * 1040 * 4 * 4;
static constexpr size_t B_PK4 = B_PK3 + 256ull * 656  * 4 * 4;
static constexpr size_t B_BAR = B_PK4 + 256ull * 512  * 4 * 4;   // 8 KB sync area
// U[0..511]: per-block arrival slots (completed-step count)
// U[512 + rep*64 .. +3]: watermark replicas rel[0..3], rep = 0..15

struct KParams {
  const float *x;
  const float *k1, *r1, *b1, *k2, *r2, *b2, *k3, *r3, *b3, *k4, *r4, *b4;
  const float *wd1, *bd1, *wd2, *bd2, *wd3, *bd3, *wd4, *bd4, *wd5, *bd5, *wd6, *bd6;
  float *out;
  char *ws;
};

__device__ __forceinline__ void fma4(float4& a, float s, const float4& w) {
  a.x += s * w.x; a.y += s * w.y; a.z += s * w.z; a.w += s * w.w;
}
__device__ __forceinline__ float sigm(float v) { return 1.f / (1.f + expf(-v)); }

// ---- agent-scope (cross-XCD coherent, MALL-backed) primitives ----
__device__ __forceinline__ uint64_t c_load8(const void* p) {
  return __hip_atomic_load((const uint64_t*)p, __ATOMIC_RELAXED, __HIP_MEMORY_SCOPE_AGENT);
}
__device__ __forceinline__ void c_store8(void* p, uint64_t v) {
  __hip_atomic_store((uint64_t*)p, v, __ATOMIC_RELAXED, __HIP_MEMORY_SCOPE_AGENT);
}
__device__ __forceinline__ void c_store4(void* p, unsigned v) {
  __hip_atomic_store((unsigned*)p, v, __ATOMIC_RELAXED, __HIP_MEMORY_SCOPE_AGENT);
}
__device__ __forceinline__ void c_store2(void* p, unsigned short v) {
  __hip_atomic_store((unsigned short*)p, v, __ATOMIC_RELAXED, __HIP_MEMORY_SCOPE_AGENT);
}
__device__ __forceinline__ unsigned short c_load2(const void* p) {
  return __hip_atomic_load((const unsigned short*)p, __ATOMIC_RELAXED, __HIP_MEMORY_SCOPE_AGENT);
}
__device__ __forceinline__ unsigned u_load(const unsigned* p) {
  return __hip_atomic_load(p, __ATOMIC_RELAXED, __HIP_MEMORY_SCOPE_AGENT);
}
__device__ __forceinline__ void u_store(unsigned* p, unsigned v) {
  __hip_atomic_store(p, v, __ATOMIC_RELAXED, __HIP_MEMORY_SCOPE_AGENT);
}

// ---------------- control block: per-layer watermark publisher ----------------
template<int TB1, int TB2, int TB3, int TB4>
__device__ void control_role(unsigned* U) {
  constexpr int TNB = TB1 + TB2 + TB3 + TB4;
  const int tid = threadIdx.x;
  auto layer_of = [](int i) {
    return (i < TB1) ? 0 : (i < TB1 + TB2) ? 1 : (i < TB1 + TB2 + TB3) ? 2 : 3;
  };
  const int i0 = tid, i1 = tid + NT;
  const int l0 = (i0 < TNB) ? layer_of(i0) : -1;
  const int l1 = (i1 < TNB) ? layer_of(i1) : -1;
  int cand0 = 1, cand1 = 1, cand2 = 1, cand3 = 1;
  for (;;) {
    bool k0 = true, k1 = true, k2 = true, k3 = true;
    if (l0 >= 0) {
      int v = (int)u_load(&U[i0]);
      int c = (l0 == 0) ? cand0 : (l0 == 1) ? cand1 : (l0 == 2) ? cand2 : cand3;
      bool ok = v >= c;
      if (l0 == 0) k0 &= ok; else if (l0 == 1) k1 &= ok; else if (l0 == 2) k2 &= ok; else k3 &= ok;
    }
    if (l1 >= 0) {
      int v = (int)u_load(&U[i1]);
      int c = (l1 == 0) ? cand0 : (l1 == 1) ? cand1 : (l1 == 2) ? cand2 : cand3;
      bool ok = v >= c;
      if (l1 == 0) k0 &= ok; else if (l1 == 1) k1 &= ok; else if (l1 == 2) k2 &= ok; else k3 &= ok;
    }
    int a0 = __syncthreads_and((int)k0);
    int a1 = __syncthreads_and((int)k1);
    int a2 = __syncthreads_and((int)k2);
    int a3 = __syncthreads_and((int)k3);
    bool prog = false;
    if (a0 && cand0 <= TSTEPS) { ++cand0; prog = true; }
    if (a1 && cand1 <= TSTEPS) { ++cand1; prog = true; }
    if (a2 && cand2 <= TSTEPS) { ++cand2; prog = true; }
    if (a3 && cand3 <= TSTEPS) { ++cand3; prog = true; }
    if (prog) {
      unsigned r0 = (unsigned)(cand0 - 1), r1 = (unsigned)(cand1 - 1);
      unsigned r2 = (unsigned)(cand2 - 1), r3 = (unsigned)(cand3 - 1);
      if (tid < 16)       c_store8(&U[512 + tid * 64],            (uint64_t)r0 | ((uint64_t)r1 << 32));
      else if (tid < 32)  c_store8(&U[512 + (tid - 16) * 64 + 2], (uint64_t)r2 | ((uint64_t)r3 << 32));
    } else {
      __builtin_amdgcn_s_sleep(1);
    }
    if (cand0 > TSTEPS && cand1 > TSTEPS && cand2 > TSTEPS && cand3 > TSTEPS) break;
  }
}

// ---------------- weight prepack: pack[blk][k][quad<NJ][gate] (f32) ----------------
__device__ void prepack_layer(const float* __restrict__ gk, const float* __restrict__ gr,
                              float* __restrict__ pack, int DIN, int H, int NJ, int NBLK,
                              int gtid, int gstr) {
  const long K = DIN + H;
  const long total = (long)NBLK * K * NJ * 4;
  for (long e = gtid; e < total; e += gstr) {
    int  g   = (int)(e & 3);
    long r   = e >> 2;
    int  q   = (int)(r % NJ);
    long r2  = r / NJ;
    int  k   = (int)(r2 % K);
    int  blk = (int)(r2 / K);
    int  j   = blk * NJ + q;
    float v = (k < DIN) ? gk[(size_t)k * 4 * H + (size_t)g * H + j]
                        : gr[(size_t)(k - DIN) * 4 * H + (size_t)g * H + j];
    pack[e] = v;
  }
}

// ---------------- persistent LSTM layer role (dataflow-synced) ----------------
template<int DIN, int H, int NJ, int LIDX, bool SEQIN>
__device__ __forceinline__ void lstm_role(int blk, int bid,
                          const f16* __restrict__ lo_base,   // xT (SEQIN) or lower-layer ring
                          f16* __restrict__ ownH,            // own ring base
                          const float* __restrict__ pack,
                          const float* __restrict__ gbias,
                          char* smem, unsigned* U) {
  constexpr int K   = DIN + H;
  constexpr int BG  = NT / NJ;
  constexpr int MB  = BATCH / BG;                  // 1, 2 or 4
  constexpr int NCH = (K + CK - 1) / CK;
  constexpr int PPT = (CK * BATCH / 4) / NT;       // 6 x 8B units / thread / chunk
  static_assert(MB == 1 || MB == 2 || MB == 4, "MB");

  const int tid = threadIdx.x;
  const int jj  = tid / BG;
  const int bg  = tid % BG;
  const int b0  = bg * MB;
  const int j   = blk * NJ + jj;

  const float* mypack = pack + (size_t)blk * K * NJ * 4;
  const float4 bias = make_float4(gbias[j], gbias[H + j], gbias[2 * H + j], gbias[3 * H + j]);
  const unsigned* relp = &U[512 + (bid & 15) * 64];

  float c[MB];
  #pragma unroll
  for (int m = 0; m < MB; ++m) c[m] = 0.f;

  f16* buf0 = (f16*)smem;
  f16* buf1 = (f16*)(smem + CK * BATCH * 2);

  // leader's cached watermark view (avoids a poll when slack already covers)
  int rc0 = 0, rc1 = 0, rc2 = 0, rc3 = 0;

  for (int t = 0; t < TSTEPS; ++t) {
    // ---- dataflow wait: input rel[LIDX-1] >= t+1, own rel[LIDX] >= t,
    //                     downstream rel[LIDX+1] >= t-3 (ring backpressure) ----
    if (tid == 0) {
      for (;;) {
        bool ok = true;
        if constexpr (LIDX == 0) ok = (rc0 >= t) && (rc1 >= t - 3);
        else if constexpr (LIDX == 1) ok = (rc0 >= t + 1) && (rc1 >= t) && (rc2 >= t - 3);
        else if constexpr (LIDX == 2) ok = (rc1 >= t + 1) && (rc2 >= t) && (rc3 >= t - 3);
        else ok = (rc2 >= t + 1) && (rc3 >= t);
        if (ok) break;
        uint64_t a = c_load8(relp);
        uint64_t b = c_load8(relp + 2);
        rc0 = (int)(unsigned)a; rc1 = (int)(a >> 32);
        rc2 = (int)(unsigned)b; rc3 = (int)(b >> 32);
      }
    }
    __syncthreads();

    const f16* src_lo = SEQIN ? (lo_base + (size_t)t * DIN * BATCH)
                              : (lo_base + (size_t)(t & (RING - 1)) * DIN * BATCH);
    const f16* src_hi = ownH + (size_t)((t - 1) & (RING - 1)) * H * BATCH;

    float4 a[MB];
    #pragma unroll
    for (int m = 0; m < MB; ++m) a[m] = make_float4(0.f, 0.f, 0.f, 0.f);

    // ---- stage chunk 0 (burst loads, then park) ----
    uint64_t tmp[PPT];
    #pragma unroll
    for (int r = 0; r < PPT; ++r) {
      const int p  = r * NT + tid;               // 8B unit; 32 units per 128-f16 row
      const int k  = p >> 5;
      const int bb = (p & 31) * 4;
      const f16* sp = (k < DIN) ? (src_lo + (size_t)k * BATCH + bb)
                                : (src_hi + (size_t)(k - DIN) * BATCH + bb);
      tmp[r] = (SEQIN && k < DIN) ? *(const uint64_t*)sp : c_load8(sp);
    }
    #pragma unroll
    for (int r = 0; r < PPT; ++r) {
      const int p = r * NT + tid;
      *(uint64_t*)((char*)buf0 + 8 * p) = tmp[r];
    }
    __syncthreads();

    for (int ch = 0; ch < NCH; ++ch) {
      f16* cur = (ch & 1) ? buf1 : buf0;
      f16* nxt = (ch & 1) ? buf0 : buf1;
      const int kb = ch * CK;
      const bool more = (ch + 1 < NCH);

      if (more) {
        const int kb2 = kb + CK;
        #pragma unroll
        for (int r = 0; r < PPT; ++r) {
          const int p  = r * NT + tid;
          const int k  = kb2 + (p >> 5);
          const int bb = (p & 31) * 4;
          if (k < K) {
            const f16* sp = (k < DIN) ? (src_lo + (size_t)k * BATCH + bb)
                                      : (src_hi + (size_t)(k - DIN) * BATCH + bb);
            tmp[r] = (SEQIN && k < DIN) ? *(const uint64_t*)sp : c_load8(sp);
          } else tmp[r] = 0ull;
        }
      }

      const int kmax = (K - kb < CK) ? (K - kb) : CK;
      const float* wrow = mypack + ((size_t)kb * NJ + jj) * 4;
      #pragma unroll 4
      for (int kl = 0; kl < kmax; ++kl) {
        float4 w = *(const float4*)(wrow + (size_t)kl * NJ * 4);
        if constexpr (MB == 4) {
          h4v hv = *(const h4v*)(cur + kl * BATCH + b0);
          fma4(a[0], (float)hv.x, w); fma4(a[1], (float)hv.y, w);
          fma4(a[2], (float)hv.z, w); fma4(a[3], (float)hv.w, w);
        } else if constexpr (MB == 2) {
          h2v hv = *(const h2v*)(cur + kl * BATCH + b0);
          fma4(a[0], (float)hv.x, w); fma4(a[1], (float)hv.y, w);
        } else {
          fma4(a[0], (float)cur[kl * BATCH + b0], w);
        }
      }

      if (more) {
        #pragma unroll
        for (int r = 0; r < PPT; ++r) {
          const int p = r * NT + tid;
          *(uint64_t*)((char*)nxt + 8 * p) = tmp[r];
        }
      }
      __syncthreads();
    }

    // ---- epilogue: gates, state, coherent f16 store into ring slot t ----
    f16* dst = ownH + (size_t)(t & (RING - 1)) * H * BATCH + (size_t)j * BATCH + b0;
    float hv[MB];
    #pragma unroll
    for (int m = 0; m < MB; ++m) {
      float ig = sigm(a[m].x + bias.x);
      float fg = sigm(a[m].y + bias.y);
      float gg = tanhf(a[m].z + bias.z);
      float og = sigm(a[m].w + bias.w);
      c[m] = fg * c[m] + ig * gg;
      hv[m] = og * tanhf(c[m]);
    }
    if constexpr (MB == 4) {
      union { f16 h[4]; uint64_t u; } o;
      o.h[0] = (f16)hv[0]; o.h[1] = (f16)hv[1]; o.h[2] = (f16)hv[2]; o.h[3] = (f16)hv[3];
      c_store8(dst, o.u);
    } else if constexpr (MB == 2) {
      union { f16 h[2]; unsigned u; } o;
      o.h[0] = (f16)hv[0]; o.h[1] = (f16)hv[1];
      c_store4(dst, o.u);
    } else {
      union { f16 h; unsigned short u; } o;
      o.h = (f16)hv[0];
      c_store2(dst, o.u);
    }

    // ---- arrival: drain h stores to coherence point, then publish slot ----
    asm volatile("s_waitcnt vmcnt(0)" ::: "memory");
    __syncthreads();
    if (tid == 0) u_store(&U[bid], (unsigned)(t + 1));
  }
}

// ---------------- dense head ----------------
__device__ void dense_stage(const float* in, float* outb,
                            const float* __restrict__ w, const float* __restrict__ bias,
                            int din, int dout, bool relu) {
  for (int jc = threadIdx.x; jc < dout; jc += NT) {
    float s = bias[jc];
    for (int d = 0; d < din; ++d) s += in[d] * w[(size_t)d * dout + jc];
    outb[jc] = relu ? fmaxf(s, 0.f) : s;
  }
  __syncthreads();
}

// ---------------- fused cooperative kernel (templated over block partition) ----------------
template<int TB1, int TB2, int TB3, int TB4>
__global__ __launch_bounds__(NT, 2) void fused_kernel(KParams p) {
  constexpr int TNB = TB1 + TB2 + TB3 + TB4;
  constexpr int NGRID = TNB + 1;
  constexpr int TRB2 = TB1, TRB3 = TB1 + TB2, TRB4 = TB1 + TB2 + TB3;
  constexpr int NJ1 = 640 / TB1, NJ2 = 400 / TB2, NJ3 = 256 / TB3, NJ4 = 256 / TB4;

  cg::grid_group grid = cg::this_grid();
  __shared__ __attribute__((aligned(16))) char smem[24576];   // 24 KB -> 2 blocks/CU

  char* ws = p.ws;
  unsigned* U = (unsigned*)(ws + B_BAR);
  const int tid  = threadIdx.x;
  const int bid  = blockIdx.x;
  const int gtid = bid * NT + tid;
  const int gstr = NGRID * NT;

  // ---- phase 0a: zero h rings ----
  {
    uint64_t* hb = (uint64_t*)(ws + B_H1);
    const size_t n = (B_HEND - B_H1) / 8;
    for (size_t i = gtid; i < n; i += gstr) hb[i] = 0ull;
  }
  // ---- phase 0b: prepack weights (f32, per-block contiguous) ----
  prepack_layer(p.k1, p.r1, (float*)(ws + B_PK1), 64,  640, NJ1, TB1, gtid, gstr);
  prepack_layer(p.k2, p.r2, (float*)(ws + B_PK2), 640, 400, NJ2, TB2, gtid, gstr);
  prepack_layer(p.k3, p.r3, (float*)(ws + B_PK3), 400, 256, NJ3, TB3, gtid, gstr);
  prepack_layer(p.k4, p.r4, (float*)(ws + B_PK4), 256, 256, NJ4, TB4, gtid, gstr);
  // ---- phase 0c: transpose x [128][512][64] f32 -> xT [512][64][128] f16 ----
  {
    float* tile = (float*)smem;          // [32][129] f32 = 16,512 B
    f16* xT = (f16*)(ws + B_XT);
    for (int t = bid; t < TSTEPS; t += NGRID) {
      #pragma unroll
      for (int pass = 0; pass < 2; ++pass) {
        const int d0 = pass * 32;
        const int b = tid >> 1, half = tid & 1;
        const float* src = p.x + ((size_t)b * TSTEPS + t) * 64 + d0 + half * 16;
        float4 v[4];
        #pragma unroll
        for (int q = 0; q < 4; ++q) v[q] = *(const float4*)(src + 4 * q);
        __syncthreads();
        #pragma unroll
        for (int q = 0; q < 4; ++q) {
          tile[(half * 16 + 4 * q + 0) * 129 + b] = v[q].x;
          tile[(half * 16 + 4 * q + 1) * 129 + b] = v[q].y;
          tile[(half * 16 + 4 * q + 2) * 129 + b] = v[q].z;
          tile[(half * 16 + 4 * q + 3) * 129 + b] = v[q].w;
        }
        __syncthreads();
        const int r = tid >> 3, seg = tid & 7;
        f16* dst = xT + ((size_t)t * 64 + d0 + r) * BATCH + seg * 16;
        h8v o0, o1;
        #pragma unroll
        for (int i = 0; i < 8; ++i) {
          o0[i] = (f16)tile[r * 129 + seg * 16 + i];
          o1[i] = (f16)tile[r * 129 + seg * 16 + 8 + i];
        }
        *(h8v*)dst = o0;
        *(h8v*)(dst + 8) = o1;
      }
    }
  }

  // one full CG sync: publish xT/packs/zeroed rings device-wide
  grid.sync();

  // ---- phase 1: dataflow-pipelined 4-layer LSTM scan ----
  if (bid == TNB) {
    control_role<TB1, TB2, TB3, TB4>(U);
  } else if (bid < TRB2) {
    lstm_role< 64, 640, NJ1, 0, true >(bid,        bid, (const f16*)(ws + B_XT),
                                       (f16*)(ws + B_H1), (const float*)(ws + B_PK1), p.b1, smem, U);
  } else if (bid < TRB3) {
    lstm_role<640, 400, NJ2, 1, false>(bid - TRB2, bid, (const f16*)(ws + B_H1),
                                       (f16*)(ws + B_H2), (const float*)(ws + B_PK2), p.b2, smem, U);
  } else if (bid < TRB4) {
    lstm_role<400, 256, NJ3, 2, false>(bid - TRB3, bid, (const f16*)(ws + B_H2),
                                       (f16*)(ws + B_H3), (const float*)(ws + B_PK3), p.b3, smem, U);
  } else {
    lstm_role<256, 256, NJ4, 3, false>(bid - TRB4, bid, (const f16*)(ws + B_H3),
                                       (f16*)(ws + B_H4), (const float*)(ws + B_PK4), p.b4, smem, U);
  }

  // ---- phase 2: dense head; wait for L4 completion via watermark ----
  if (bid < BATCH) {
    if (tid == 0) {
      const unsigned* relp = &U[512 + (bid & 15) * 64];
      for (;;) {
        uint64_t b23 = c_load8(relp + 2);
        if ((int)(b23 >> 32) >= TSTEPS) break;
      }
    }
    __syncthreads();
    const int b = bid;
    float* A = (float*)smem;
    float* B = (float*)smem + 512;
    const f16* h4 = (const f16*)(ws + B_H4) + (size_t)((TSTEPS - 1) & (RING - 1)) * 256 * BATCH;
    for (int d = tid; d < 256; d += NT) {
      union { unsigned short u; f16 h; } cc;
      cc.u = c_load2(h4 + (size_t)d * BATCH + b);
      A[d] = (float)cc.h;
    }
    __syncthreads();
    dense_stage(A, B, p.wd1, p.bd1, 256, 512, true);
    dense_stage(B, A, p.wd2, p.bd2, 512, 256, true);
    dense_stage(A, B, p.wd3, p.bd3, 256, 128, true);
    dense_stage(B, A, p.wd4, p.bd4, 128, 64,  true);
    dense_stage(A, B, p.wd5, p.bd5, 64,  16,  true);
    dense_stage(B, A, p.wd6, p.bd6, 16,  3,   false);
    if (tid == 0) {
      float z0 = A[0], z1 = A[1], z2 = A[2];
      float m  = fmaxf(fmaxf(z0, z1), z2);
      float e0 = expf(z0 - m), e1 = expf(z1 - m), e2 = expf(z2 - m);
      float s  = e0 + e1 + e2;
      p.out[b * 3 + 0] = e0 / s;
      p.out[b * 3 + 1] = e1 / s;
      p.out[b * 3 + 2] = e2 / s;
    }
  }
}

// ---------------- launch: occupancy-validated config selection ----------------
extern "C" void kernel_launch(void* const* d_in, const int* in_sizes, int n_in,
                              void* d_out, int out_size, void* d_ws, size_t ws_size,
                              hipStream_t stream) {
  KParams prm;
  prm.x  = (const float*)d_in[0];
  prm.k1 = (const float*)d_in[1];  prm.r1 = (const float*)d_in[2];  prm.b1 = (const float*)d_in[3];
  prm.k2 = (const float*)d_in[4];  prm.r2 = (const float*)d_in[5];  prm.b2 = (const float*)d_in[6];
  prm.k3 = (const float*)d_in[7];  prm.r3 = (const float*)d_in[8];  prm.b3 = (const float*)d_in[9];
  prm.k4 = (const float*)d_in[10]; prm.r4 = (const float*)d_in[11]; prm.b4 = (const float*)d_in[12];
  prm.wd1 = (const float*)d_in[13]; prm.bd1 = (const float*)d_in[14];
  prm.wd2 = (const float*)d_in[15]; prm.bd2 = (const float*)d_in[16];
  prm.wd3 = (const float*)d_in[17]; prm.bd3 = (const float*)d_in[18];
  prm.wd4 = (const float*)d_in[19]; prm.bd4 = (const float*)d_in[20];
  prm.wd5 = (const float*)d_in[21]; prm.bd5 = (const float*)d_in[22];
  prm.wd6 = (const float*)d_in[23]; prm.bd6 = (const float*)d_in[24];
  prm.out = (float*)d_out;
  prm.ws  = (char*)d_ws;

  // zero arrival slots + watermark replicas (ws re-poisoned 0xAA before every launch)
  hipMemsetAsync((char*)d_ws + B_BAR, 0, 8192, stream);

  int maxb = 0;
  hipOccupancyMaxActiveBlocksPerMultiprocessor(
      &maxb, (const void*)fused_kernel<160, 200, 64, 64>, NT, 0);

  void* args[] = { &prm };
  if (maxb >= 2) {
    hipLaunchCooperativeKernel((void*)fused_kernel<160, 200, 64, 64>,
                               dim3(489), dim3(NT), args, 0, stream);
  } else {
    hipLaunchCooperativeKernel((void*)fused_kernel<80, 100, 32, 32>,
                               dim3(245), dim3(NT), args, 0, stream);
  }
}

// Round 9
// 37875.217 us; speedup vs baseline: 1.6323x; 1.6323x over previous
//
#include <hip/hip_runtime.h>
#include <hip/hip_cooperative_groups.h>
#include <cstdint>
#include <cstddef>

namespace cg = cooperative_groups;

typedef _Float16 f16;
typedef _Float16 h2v __attribute__((ext_vector_type(2)));
typedef _Float16 h4v __attribute__((ext_vector_type(4)));
typedef _Float16 h8v __attribute__((ext_vector_type(8)));

static constexpr int BATCH = 128;
static constexpr int TSTEPS = 512;
static constexpr int NT = 256;
static constexpr int CK = 48;          // k-rows per staged chunk (12 KB f16)

// ---------------- workspace layout (byte offsets), parametrized by ring depth ----
template<int RING> struct WS {
  static constexpr size_t XT  = 0;                                // f16 [512][64][128]
  static constexpr size_t H1  = XT + 512ull * 64 * 128 * 2;       // f16 [RING][H][128]
  static constexpr size_t H2  = H1 + (size_t)RING * 640 * 128 * 2;
  static constexpr size_t H3  = H2 + (size_t)RING * 400 * 128 * 2;
  static constexpr size_t H4  = H3 + (size_t)RING * 256 * 128 * 2;
  static constexpr size_t PK1 = H4 + (size_t)RING * 256 * 128 * 2; // f32 packs
  static constexpr size_t PK2 = PK1 + 640ull * 704  * 4 * 4;
  static constexpr size_t PK3 = PK2 + 400ull * 1040 * 4 * 4;
  static constexpr size_t PK4 = PK3 + 256ull * 656  * 4 * 4;
  static constexpr size_t BAR = PK4 + 256ull * 512  * 4 * 4;      // 8 KB sync area
  static constexpr size_t END = BAR + 8192;
};
// U[0..511]: per-block arrival slots; U[512 + rep*64 + l]: rel[l] replicas, rep=0..15

struct KParams {
  const float *x;
  const float *k1, *r1, *b1, *k2, *r2, *b2, *k3, *r3, *b3, *k4, *r4, *b4;
  const float *wd1, *bd1, *wd2, *bd2, *wd3, *bd3, *wd4, *bd4, *wd5, *bd5, *wd6, *bd6;
  float *out;
  char *ws;
};

__device__ __forceinline__ void fma4(float4& a, float s, const float4& w) {
  a.x += s * w.x; a.y += s * w.y; a.z += s * w.z; a.w += s * w.w;
}
__device__ __forceinline__ float sigm(float v) { return 1.f / (1.f + expf(-v)); }

// ---- agent-scope (cross-XCD coherent; bypasses L1/L2) primitives ----
__device__ __forceinline__ uint64_t c_load8(const void* p) {
  return __hip_atomic_load((const uint64_t*)p, __ATOMIC_RELAXED, __HIP_MEMORY_SCOPE_AGENT);
}
__device__ __forceinline__ void c_store8(void* p, uint64_t v) {
  __hip_atomic_store((uint64_t*)p, v, __ATOMIC_RELAXED, __HIP_MEMORY_SCOPE_AGENT);
}
__device__ __forceinline__ void c_store4(void* p, unsigned v) {
  __hip_atomic_store((unsigned*)p, v, __ATOMIC_RELAXED, __HIP_MEMORY_SCOPE_AGENT);
}
__device__ __forceinline__ void c_store2(void* p, unsigned short v) {
  __hip_atomic_store((unsigned short*)p, v, __ATOMIC_RELAXED, __HIP_MEMORY_SCOPE_AGENT);
}
__device__ __forceinline__ unsigned short c_load2(const void* p) {
  return __hip_atomic_load((const unsigned short*)p, __ATOMIC_RELAXED, __HIP_MEMORY_SCOPE_AGENT);
}
__device__ __forceinline__ unsigned u_load(const unsigned* p) {
  return __hip_atomic_load(p, __ATOMIC_RELAXED, __HIP_MEMORY_SCOPE_AGENT);
}
__device__ __forceinline__ void u_store(unsigned* p, unsigned v) {
  __hip_atomic_store(p, v, __ATOMIC_RELAXED, __HIP_MEMORY_SCOPE_AGENT);
}

// ---------------- per-layer control block: publish watermark rel[lidx] ----------------
template<int NBLK>
__device__ void control_role(unsigned* U, int first, int lidx) {
  const int tid = threadIdx.x;
  int cand = 1;
  while (cand <= TSTEPS) {
    unsigned v = (tid < NBLK) ? u_load(&U[first + tid]) : 0xFFFFFFFFu;
    if (__syncthreads_and((int)(v >= (unsigned)cand))) {
      if (tid < 16) u_store(&U[512 + tid * 64 + lidx], (unsigned)cand);
      ++cand;
    }
  }
}

// ---------------- weight prepack: pack[blk][k][quad<NJ][gate] (f32) ----------------
__device__ void prepack_layer(const float* __restrict__ gk, const float* __restrict__ gr,
                              float* __restrict__ pack, int DIN, int H, int NJ, int NBLK,
                              int gtid, int gstr) {
  const long K = DIN + H;
  const long total = (long)NBLK * K * NJ * 4;
  for (long e = gtid; e < total; e += gstr) {
    int  g   = (int)(e & 3);
    long r   = e >> 2;
    int  q   = (int)(r % NJ);
    long r2  = r / NJ;
    int  k   = (int)(r2 % K);
    int  blk = (int)(r2 / K);
    int  j   = blk * NJ + q;
    float v = (k < DIN) ? gk[(size_t)k * 4 * H + (size_t)g * H + j]
                        : gr[(size_t)(k - DIN) * 4 * H + (size_t)g * H + j];
    pack[e] = v;
  }
}

// ---------------- persistent LSTM layer role ----------------
// RING==TSTEPS: addresses never reused -> consumers use PLAIN (L2-cacheable) loads.
// RING<TSTEPS: slot reuse -> sc1 loads + downstream backpressure.
template<int DIN, int H, int NJ, int LIDX, bool SEQIN, int RING>
__device__ __forceinline__ void lstm_role(int blk, int bid,
                          const f16* __restrict__ lo_base,
                          f16* __restrict__ ownH,
                          const float* __restrict__ pack,
                          const float* __restrict__ gbias,
                          char* smem, unsigned* U) {
  constexpr bool SEQM = (RING == TSTEPS);
  constexpr int K   = DIN + H;
  constexpr int BG  = NT / NJ;
  constexpr int MB  = BATCH / BG;                  // 1, 2 or 4
  constexpr int NCH = (K + CK - 1) / CK;
  constexpr int PPT = (CK * BATCH / 4) / NT;       // 6 x 8B units / thread / chunk
  static_assert(MB == 1 || MB == 2 || MB == 4, "MB");

  const int tid = threadIdx.x;
  const int jj  = tid / BG;
  const int bg  = tid % BG;
  const int b0  = bg * MB;
  const int j   = blk * NJ + jj;

  const float* mypack = pack + (size_t)blk * K * NJ * 4;
  const float4 bias = make_float4(gbias[j], gbias[H + j], gbias[2 * H + j], gbias[3 * H + j]);
  const unsigned* relp = &U[512 + (bid & 15) * 64];

  float c[MB];
  #pragma unroll
  for (int m = 0; m < MB; ++m) c[m] = 0.f;

  f16* buf0 = (f16*)smem;
  f16* buf1 = (f16*)(smem + CK * BATCH * 2);

  int rcI = 0, rcO = 0, rcD = 0;   // leader-cached watermarks (upstream/own/downstream)

  for (int t = 0; t < TSTEPS; ++t) {
    // ---- dataflow wait ----
    if (tid == 0) {
      for (;;) {
        bool ok = (rcO >= t);
        if constexpr (LIDX > 0) ok = ok && (rcI >= t + 1);
        if constexpr (!SEQM && LIDX < 3) ok = ok && (rcD >= t - (RING - 1));
        if (ok) break;
        if constexpr (LIDX > 0) rcI = (int)u_load(&relp[LIDX - 1]);
        rcO = (int)u_load(&relp[LIDX]);
        if constexpr (!SEQM && LIDX < 3) rcD = (int)u_load(&relp[LIDX + 1]);
      }
    }
    __syncthreads();

    const f16* src_lo = SEQIN ? (lo_base + (size_t)t * DIN * BATCH)
                              : (lo_base + (size_t)(t & (RING - 1)) * DIN * BATCH);
    const f16* src_hi = ownH + (size_t)((t - 1) & (RING - 1)) * H * BATCH;

    float4 a[MB];
    #pragma unroll
    for (int m = 0; m < MB; ++m) a[m] = make_float4(0.f, 0.f, 0.f, 0.f);

    // staged-load helper: 8B unit at row k, f16-col bb
    auto ld = [&](int k, int bb) -> uint64_t {
      if (k < DIN) {
        const f16* sp = src_lo + (size_t)k * BATCH + bb;
        if constexpr (SEQIN || SEQM) return *(const uint64_t*)sp;  // fresh-address / xT
        else return c_load8(sp);
      } else {
        if (t == 0) return 0ull;                    // h_{-1} == 0: skip, never read
        const f16* sp = src_hi + (size_t)(k - DIN) * BATCH + bb;
        if constexpr (SEQM) return *(const uint64_t*)sp;
        else return c_load8(sp);
      }
    };

    // ---- stage chunk 0 (burst loads, then park) ----
    uint64_t tmp[PPT];
    #pragma unroll
    for (int r = 0; r < PPT; ++r) {
      const int p = r * NT + tid;                  // 32 x 8B units per 128-f16 row
      tmp[r] = ld(p >> 5, (p & 31) * 4);
    }
    #pragma unroll
    for (int r = 0; r < PPT; ++r) {
      const int p = r * NT + tid;
      *(uint64_t*)((char*)buf0 + 8 * p) = tmp[r];
    }
    __syncthreads();

    for (int ch = 0; ch < NCH; ++ch) {
      f16* cur = (ch & 1) ? buf1 : buf0;
      f16* nxt = (ch & 1) ? buf0 : buf1;
      const int kb = ch * CK;
      const bool more = (ch + 1 < NCH);

      if (more) {
        const int kb2 = kb + CK;
        #pragma unroll
        for (int r = 0; r < PPT; ++r) {
          const int p = r * NT + tid;
          const int k = kb2 + (p >> 5);
          tmp[r] = (k < K) ? ld(k, (p & 31) * 4) : 0ull;
        }
      }

      const int kmax = (K - kb < CK) ? (K - kb) : CK;
      const float* wrow = mypack + ((size_t)kb * NJ + jj) * 4;
      #pragma unroll 4
      for (int kl = 0; kl < kmax; ++kl) {
        float4 w = *(const float4*)(wrow + (size_t)kl * NJ * 4);
        if constexpr (MB == 4) {
          h4v hv = *(const h4v*)(cur + kl * BATCH + b0);
          fma4(a[0], (float)hv.x, w); fma4(a[1], (float)hv.y, w);
          fma4(a[2], (float)hv.z, w); fma4(a[3], (float)hv.w, w);
        } else if constexpr (MB == 2) {
          h2v hv = *(const h2v*)(cur + kl * BATCH + b0);
          fma4(a[0], (float)hv.x, w); fma4(a[1], (float)hv.y, w);
        } else {
          fma4(a[0], (float)cur[kl * BATCH + b0], w);
        }
      }

      if (more) {
        #pragma unroll
        for (int r = 0; r < PPT; ++r) {
          const int p = r * NT + tid;
          *(uint64_t*)((char*)nxt + 8 * p) = tmp[r];
        }
      }
      __syncthreads();
    }

    // ---- epilogue: gates, state, sc1 h store into slot t ----
    f16* dst = ownH + (size_t)(t & (RING - 1)) * H * BATCH + (size_t)j * BATCH + b0;
    float hv[MB];
    #pragma unroll
    for (int m = 0; m < MB; ++m) {
      float ig = sigm(a[m].x + bias.x);
      float fg = sigm(a[m].y + bias.y);
      float gg = tanhf(a[m].z + bias.z);
      float og = sigm(a[m].w + bias.w);
      c[m] = fg * c[m] + ig * gg;
      hv[m] = og * tanhf(c[m]);
    }
    if constexpr (MB == 4) {
      union { f16 h[4]; uint64_t u; } o;
      o.h[0] = (f16)hv[0]; o.h[1] = (f16)hv[1]; o.h[2] = (f16)hv[2]; o.h[3] = (f16)hv[3];
      c_store8(dst, o.u);
    } else if constexpr (MB == 2) {
      union { f16 h[2]; unsigned u; } o;
      o.h[0] = (f16)hv[0]; o.h[1] = (f16)hv[1];
      c_store4(dst, o.u);
    } else {
      union { f16 h; unsigned short u; } o;
      o.h = (f16)hv[0];
      c_store2(dst, o.u);
    }

    // ---- arrival: drain sc1 stores to coherence point, publish slot ----
    asm volatile("s_waitcnt vmcnt(0)" ::: "memory");
    __syncthreads();
    if (tid == 0) u_store(&U[bid], (unsigned)(t + 1));
  }
}

// ---------------- dense head ----------------
__device__ void dense_stage(const float* in, float* outb,
                            const float* __restrict__ w, const float* __restrict__ bias,
                            int din, int dout, bool relu) {
  for (int jc = threadIdx.x; jc < dout; jc += NT) {
    float s = bias[jc];
    for (int d = 0; d < din; ++d) s += in[d] * w[(size_t)d * dout + jc];
    outb[jc] = relu ? fmaxf(s, 0.f) : s;
  }
  __syncthreads();
}

// ---------------- fused cooperative kernel ----------------
template<int TB1, int TB2, int TB3, int TB4, int RING>
__global__ __launch_bounds__(NT, 2) void fused_kernel(KParams p) {
  constexpr int TNB = TB1 + TB2 + TB3 + TB4;
  constexpr int NGRID = TNB + 4;                   // + 4 per-layer control blocks
  constexpr int TRB2 = TB1, TRB3 = TB1 + TB2, TRB4 = TB1 + TB2 + TB3;
  constexpr int NJ1 = 640 / TB1, NJ2 = 400 / TB2, NJ3 = 256 / TB3, NJ4 = 256 / TB4;
  using L = WS<RING>;

  cg::grid_group grid = cg::this_grid();
  __shared__ __attribute__((aligned(16))) char smem[24576];   // 24 KB -> 2 blocks/CU

  char* ws = p.ws;
  unsigned* U = (unsigned*)(ws + L::BAR);
  const int tid  = threadIdx.x;
  const int bid  = blockIdx.x;
  const int gtid = bid * NT + tid;
  const int gstr = NGRID * NT;

  // ---- phase 0a: prepack weights (f32, per-block contiguous) ----
  prepack_layer(p.k1, p.r1, (float*)(ws + L::PK1), 64,  640, NJ1, TB1, gtid, gstr);
  prepack_layer(p.k2, p.r2, (float*)(ws + L::PK2), 640, 400, NJ2, TB2, gtid, gstr);
  prepack_layer(p.k3, p.r3, (float*)(ws + L::PK3), 400, 256, NJ3, TB3, gtid, gstr);
  prepack_layer(p.k4, p.r4, (float*)(ws + L::PK4), 256, 256, NJ4, TB4, gtid, gstr);
  // ---- phase 0b: transpose x [128][512][64] f32 -> xT [512][64][128] f16 ----
  {
    float* tile = (float*)smem;          // [32][129] f32 = 16,512 B
    f16* xT = (f16*)(ws + L::XT);
    for (int t = bid; t < TSTEPS; t += NGRID) {
      #pragma unroll
      for (int pass = 0; pass < 2; ++pass) {
        const int d0 = pass * 32;
        const int b = tid >> 1, half = tid & 1;
        const float* src = p.x + ((size_t)b * TSTEPS + t) * 64 + d0 + half * 16;
        float4 v[4];
        #pragma unroll
        for (int q = 0; q < 4; ++q) v[q] = *(const float4*)(src + 4 * q);
        __syncthreads();
        #pragma unroll
        for (int q = 0; q < 4; ++q) {
          tile[(half * 16 + 4 * q + 0) * 129 + b] = v[q].x;
          tile[(half * 16 + 4 * q + 1) * 129 + b] = v[q].y;
          tile[(half * 16 + 4 * q + 2) * 129 + b] = v[q].z;
          tile[(half * 16 + 4 * q + 3) * 129 + b] = v[q].w;
        }
        __syncthreads();
        const int r = tid >> 3, seg = tid & 7;
        f16* dst = xT + ((size_t)t * 64 + d0 + r) * BATCH + seg * 16;
        h8v o0, o1;
        #pragma unroll
        for (int i = 0; i < 8; ++i) {
          o0[i] = (f16)tile[r * 129 + seg * 16 + i];
          o1[i] = (f16)tile[r * 129 + seg * 16 + 8 + i];
        }
        *(h8v*)dst = o0;
        *(h8v*)(dst + 8) = o1;
      }
    }
  }

  // one full CG sync: publish packs/xT device-wide; invalidates all L1/L2
  grid.sync();

  // ---- phase 1: dataflow-pipelined 4-layer LSTM scan ----
  if (bid >= TNB) {
    const int l = bid - TNB;
    if (l == 0)      control_role<TB1>(U, 0,    0);
    else if (l == 1) control_role<TB2>(U, TRB2, 1);
    else if (l == 2) control_role<TB3>(U, TRB3, 2);
    else             control_role<TB4>(U, TRB4, 3);
  } else if (bid < TRB2) {
    lstm_role< 64, 640, NJ1, 0, true , RING>(bid,        bid, (const f16*)(ws + L::XT),
                                       (f16*)(ws + L::H1), (const float*)(ws + L::PK1), p.b1, smem, U);
  } else if (bid < TRB3) {
    lstm_role<640, 400, NJ2, 1, false, RING>(bid - TRB2, bid, (const f16*)(ws + L::H1),
                                       (f16*)(ws + L::H2), (const float*)(ws + L::PK2), p.b2, smem, U);
  } else if (bid < TRB4) {
    lstm_role<400, 256, NJ3, 2, false, RING>(bid - TRB3, bid, (const f16*)(ws + L::H2),
                                       (f16*)(ws + L::H3), (const float*)(ws + L::PK3), p.b3, smem, U);
  } else {
    lstm_role<256, 256, NJ4, 3, false, RING>(bid - TRB4, bid, (const f16*)(ws + L::H3),
                                       (f16*)(ws + L::H4), (const float*)(ws + L::PK4), p.b4, smem, U);
  }

  // ---- phase 2: dense head; wait for L4 completion, read h4 slot T-1 via sc1 ----
  if (bid < BATCH) {
    if (tid == 0) {
      const unsigned* relp = &U[512 + (bid & 15) * 64];
      while ((int)u_load(&relp[3]) < TSTEPS) {}
    }
    __syncthreads();
    const int b = bid;
    float* A = (float*)smem;
    float* B = (float*)smem + 512;
    const f16* h4 = (const f16*)(ws + L::H4)
                  + (size_t)((TSTEPS - 1) & (RING - 1)) * 256 * BATCH;
    for (int d = tid; d < 256; d += NT) {
      union { unsigned short u; f16 h; } cc;
      cc.u = c_load2(h4 + (size_t)d * BATCH + b);
      A[d] = (float)cc.h;
    }
    __syncthreads();
    dense_stage(A, B, p.wd1, p.bd1, 256, 512, true);
    dense_stage(B, A, p.wd2, p.bd2, 512, 256, true);
    dense_stage(A, B, p.wd3, p.bd3, 256, 128, true);
    dense_stage(B, A, p.wd4, p.bd4, 128, 64,  true);
    dense_stage(A, B, p.wd5, p.bd5, 64,  16,  true);
    dense_stage(B, A, p.wd6, p.bd6, 16,  3,   false);
    if (tid == 0) {
      float z0 = A[0], z1 = A[1], z2 = A[2];
      float m  = fmaxf(fmaxf(z0, z1), z2);
      float e0 = expf(z0 - m), e1 = expf(z1 - m), e2 = expf(z2 - m);
      float s  = e0 + e1 + e2;
      p.out[b * 3 + 0] = e0 / s;
      p.out[b * 3 + 1] = e1 / s;
      p.out[b * 3 + 2] = e2 / s;
    }
  }
}

// ---------------- launch: ws-size + occupancy validated config selection ----------------
extern "C" void kernel_launch(void* const* d_in, const int* in_sizes, int n_in,
                              void* d_out, int out_size, void* d_ws, size_t ws_size,
                              hipStream_t stream) {
  KParams prm;
  prm.x  = (const float*)d_in[0];
  prm.k1 = (const float*)d_in[1];  prm.r1 = (const float*)d_in[2];  prm.b1 = (const float*)d_in[3];
  prm.k2 = (const float*)d_in[4];  prm.r2 = (const float*)d_in[5];  prm.b2 = (const float*)d_in[6];
  prm.k3 = (const float*)d_in[7];  prm.r3 = (const float*)d_in[8];  prm.b3 = (const float*)d_in[9];
  prm.k4 = (const float*)d_in[10]; prm.r4 = (const float*)d_in[11]; prm.b4 = (const float*)d_in[12];
  prm.wd1 = (const float*)d_in[13]; prm.bd1 = (const float*)d_in[14];
  prm.wd2 = (const float*)d_in[15]; prm.bd2 = (const float*)d_in[16];
  prm.wd3 = (const float*)d_in[17]; prm.bd3 = (const float*)d_in[18];
  prm.wd4 = (const float*)d_in[19]; prm.bd4 = (const float*)d_in[20];
  prm.wd5 = (const float*)d_in[21]; prm.bd5 = (const float*)d_in[22];
  prm.wd6 = (const float*)d_in[23]; prm.bd6 = (const float*)d_in[24];
  prm.out = (float*)d_out;
  prm.ws  = (char*)d_ws;

  const bool big = ws_size >= WS<TSTEPS>::END;     // 230.5 MB needed for seq mode
  const size_t bar_off = big ? WS<TSTEPS>::BAR : WS<4>::BAR;
  hipMemsetAsync((char*)d_ws + bar_off, 0, 8192, stream);

  int maxb = 0;
  hipOccupancyMaxActiveBlocksPerMultiprocessor(
      &maxb, (const void*)fused_kernel<160, 200, 64, 64, TSTEPS>, NT, 0);

  void* args[] = { &prm };
  if (maxb >= 2) {
    if (big) hipLaunchCooperativeKernel((void*)fused_kernel<160, 200, 64, 64, TSTEPS>,
                                        dim3(492), dim3(NT), args, 0, stream);
    else     hipLaunchCooperativeKernel((void*)fused_kernel<160, 200, 64, 64, 4>,
                                        dim3(492), dim3(NT), args, 0, stream);
  } else {
    if (big) hipLaunchCooperativeKernel((void*)fused_kernel<80, 100, 32, 32, TSTEPS>,
                                        dim3(248), dim3(NT), args, 0, stream);
    else     hipLaunchCooperativeKernel((void*)fused_kernel<80, 100, 32, 32, 4>,
                                        dim3(248), dim3(NT), args, 0, stream);
  }
}

// Round 10
// 16462.126 us; speedup vs baseline: 3.7554x; 2.3007x over previous
//
#include <hip/hip_runtime.h>
#include <hip/hip_cooperative_groups.h>
#include <cstdint>
#include <cstddef>

namespace cg = cooperative_groups;

typedef _Float16 f16;
typedef _Float16 h2v __attribute__((ext_vector_type(2)));
typedef _Float16 h8v __attribute__((ext_vector_type(8)));

static constexpr int BATCH = 128;
static constexpr int TSTEPS = 512;
static constexpr int NT = 256;

// ---------------- workspace layout (byte offsets), f16 packs ----------------
template<int RING> struct WS {
  static constexpr size_t XT  = 0;                                // f16 [512][64][128]
  static constexpr size_t H1  = XT + 512ull * 64 * 128 * 2;       // f16 [RING][H][128]
  static constexpr size_t H2  = H1 + (size_t)RING * 640 * 128 * 2;
  static constexpr size_t H3  = H2 + (size_t)RING * 400 * 128 * 2;
  static constexpr size_t H4  = H3 + (size_t)RING * 256 * 128 * 2;
  static constexpr size_t PK1 = H4 + (size_t)RING * 256 * 128 * 2; // f16 kpair packs
  static constexpr size_t PK2 = PK1 + 2ull * 704  * 640 * 4;
  static constexpr size_t PK3 = PK2 + 2ull * 1040 * 400 * 4;
  static constexpr size_t PK4 = PK3 + 2ull * 656  * 256 * 4;
  static constexpr size_t BAR = PK4 + 2ull * 512  * 256 * 4;      // 8 KB sync area
  static constexpr size_t END = BAR + 8192;
};
// U[0..511]: per-block arrival slots; U[512 + rep*64 + l]: rel[l] replicas

struct KParams {
  const float *x;
  const float *k1, *r1, *b1, *k2, *r2, *b2, *k3, *r3, *b3, *k4, *r4, *b4;
  const float *wd1, *bd1, *wd2, *bd2, *wd3, *bd3, *wd4, *bd4, *wd5, *bd5, *wd6, *bd6;
  float *out;
  char *ws;
};

__device__ __forceinline__ float sigm(float v) { return 1.f / (1.f + expf(-v)); }

__device__ __forceinline__ float dot2(h2v a, h2v b, float c) {
#if __has_builtin(__builtin_amdgcn_fdot2)
  return __builtin_amdgcn_fdot2(a, b, c, false);
#else
  return c + (float)a.x * (float)b.x + (float)a.y * (float)b.y;
#endif
}

// ---- agent-scope (cross-XCD coherent) primitives ----
__device__ __forceinline__ uint64_t c_load8(const void* p) {
  return __hip_atomic_load((const uint64_t*)p, __ATOMIC_RELAXED, __HIP_MEMORY_SCOPE_AGENT);
}
__device__ __forceinline__ void c_store8(void* p, uint64_t v) {
  __hip_atomic_store((uint64_t*)p, v, __ATOMIC_RELAXED, __HIP_MEMORY_SCOPE_AGENT);
}
__device__ __forceinline__ void c_store4(void* p, unsigned v) {
  __hip_atomic_store((unsigned*)p, v, __ATOMIC_RELAXED, __HIP_MEMORY_SCOPE_AGENT);
}
__device__ __forceinline__ void c_store2(void* p, unsigned short v) {
  __hip_atomic_store((unsigned short*)p, v, __ATOMIC_RELAXED, __HIP_MEMORY_SCOPE_AGENT);
}
__device__ __forceinline__ unsigned short c_load2(const void* p) {
  return __hip_atomic_load((const unsigned short*)p, __ATOMIC_RELAXED, __HIP_MEMORY_SCOPE_AGENT);
}
__device__ __forceinline__ unsigned u_load(const unsigned* p) {
  return __hip_atomic_load(p, __ATOMIC_RELAXED, __HIP_MEMORY_SCOPE_AGENT);
}
__device__ __forceinline__ void u_store(unsigned* p, unsigned v) {
  __hip_atomic_store(p, v, __ATOMIC_RELAXED, __HIP_MEMORY_SCOPE_AGENT);
}

// ---------------- per-layer control block: publish watermark rel[lidx] ----------------
template<int NBLK>
__device__ void control_role(unsigned* U, int first, int lidx) {
  const int tid = threadIdx.x;
  int cand = 1;
  while (cand <= TSTEPS) {
    unsigned v = (tid < NBLK) ? u_load(&U[first + tid]) : 0xFFFFFFFFu;
    if (__syncthreads_and((int)(v >= (unsigned)cand))) {
      if (tid < 16) u_store(&U[512 + tid * 64 + lidx], (unsigned)cand);
      ++cand;
    }
  }
}

// ---------------- weight prepack: f16, kpair-interleaved ----------------
// pack[blk][kp][jj][gate][e2]  (8 f16 per (kp,jj) = 16 B)
__device__ void prepack_layer(const float* __restrict__ gk, const float* __restrict__ gr,
                              f16* __restrict__ pack, int DIN, int H, int NJ, int NBLK,
                              int gtid, int gstr) {
  const long K = DIN + H;
  const long total = (long)NBLK * K * NJ * 4;      // f16 elements
  for (long e = gtid; e < total; e += gstr) {
    int  sub = (int)(e & 7);
    int  e2  = sub & 1;
    int  g   = sub >> 1;
    long r   = e >> 3;
    int  jj  = (int)(r % NJ);
    long r2  = r / NJ;
    int  kp  = (int)(r2 % (K / 2));
    int  blk = (int)(r2 / (K / 2));
    int  k   = 2 * kp + e2;
    int  j   = blk * NJ + jj;
    float v = (k < DIN) ? gk[(size_t)k * 4 * H + (size_t)g * H + j]
                        : gr[(size_t)(k - DIN) * 4 * H + (size_t)g * H + j];
    pack[e] = (f16)v;
  }
}

// ---------------- persistent LSTM layer role (LDS weights + dot2) ----------------
template<int DIN, int H, int NJ, int LIDX, bool SEQIN, int RING, int CK>
__device__ __forceinline__ void lstm_role(int blk, int bid,
                          const f16* __restrict__ lo_base,
                          f16* __restrict__ ownH,
                          const f16* __restrict__ pack,
                          const float* __restrict__ gbias,
                          char* smem, unsigned* U) {
  constexpr bool SEQM = (RING == TSTEPS);
  constexpr int K   = DIN + H;
  constexpr int KP  = K / 2;
  constexpr int BG  = NT / NJ;
  constexpr int MB  = BATCH / BG;                  // 1, 2 or 4
  constexpr int NCH = (K + CK - 1) / CK;
  constexpr int PPT = CK / 16;                     // 16B park units / thread / chunk
  static_assert(MB == 1 || MB == 2 || MB == 4, "MB");
  static_assert((K & 1) == 0, "K even");

  const int tid = threadIdx.x;
  const int jj  = tid / BG;
  const int bg  = tid % BG;
  const int b0  = bg * MB;                         // pair index (=batch index)
  const int j   = blk * NJ + jj;

  const float4 bias = make_float4(gbias[j], gbias[H + j], gbias[2 * H + j], gbias[3 * H + j]);
  const unsigned* relp = &U[512 + (bid & 15) * 64];

  // ---- LDS partition: [weights f16 | buf0 pairs | buf1 pairs] ----
  f16*      wlds = (f16*)smem;
  unsigned* buf0 = (unsigned*)(smem + (size_t)KP * NJ * 16);
  unsigned* buf1 = buf0 + (CK / 2) * BATCH;

  // ---- load this block's weights into LDS once ----
  {
    const uint4* gsrc = (const uint4*)(pack + (size_t)blk * K * NJ * 4);
    uint4* wdst = (uint4*)wlds;
    for (int i = tid; i < KP * NJ; i += NT) wdst[i] = gsrc[i];
  }
  __syncthreads();

  float c[MB];
  #pragma unroll
  for (int m = 0; m < MB; ++m) c[m] = 0.f;

  int rcI = 0, rcO = 0, rcD = 0;

  for (int t = 0; t < TSTEPS; ++t) {
    // ---- dataflow wait ----
    if (tid == 0) {
      for (;;) {
        bool ok = (rcO >= t);
        if constexpr (LIDX > 0) ok = ok && (rcI >= t + 1);
        if constexpr (!SEQM && LIDX < 3) ok = ok && (rcD >= t - (RING - 1));
        if (ok) break;
        if constexpr (LIDX > 0) rcI = (int)u_load(&relp[LIDX - 1]);
        rcO = (int)u_load(&relp[LIDX]);
        if constexpr (!SEQM && LIDX < 3) rcD = (int)u_load(&relp[LIDX + 1]);
      }
    }
    __syncthreads();

    const f16* src_lo = SEQIN ? (lo_base + (size_t)t * DIN * BATCH)
                              : (lo_base + (size_t)(t & (RING - 1)) * DIN * BATCH);
    const f16* src_hi = ownH + (size_t)((t - 1) & (RING - 1)) * H * BATCH;

    float4 a[MB];
    #pragma unroll
    for (int m = 0; m < MB; ++m) a[m] = make_float4(0.f, 0.f, 0.f, 0.f);

    // 8B load of 4 f16 from row k at batch col bb
    auto ld8 = [&](int k, int bb) -> uint64_t {
      if (k >= K) return 0ull;
      if (k < DIN) {
        const f16* sp = src_lo + (size_t)k * BATCH + bb;
        if constexpr (SEQIN || SEQM) return *(const uint64_t*)sp;
        else return c_load8(sp);
      } else {
        if (t == 0) return 0ull;                   // h_{-1} == 0 (never read)
        const f16* sp = src_hi + (size_t)(k - DIN) * BATCH + bb;
        if constexpr (SEQM) return *(const uint64_t*)sp;
        else return c_load8(sp);
      }
    };
    // park 16B unit u (kpair-interleaved pairs) into buf
    auto park = [&](unsigned* buf, int u, uint64_t lo, uint64_t hi) {
      union { unsigned short s[4]; uint64_t v; } L, Hh;
      L.v = lo; Hh.v = hi;
      union { unsigned short s[8]; uint4 v; } o;
      #pragma unroll
      for (int i = 0; i < 4; ++i) { o.s[2 * i] = L.s[i]; o.s[2 * i + 1] = Hh.s[i]; }
      const int kp = u >> 5, bb = (u & 31) * 4;
      *(uint4*)((char*)buf + ((size_t)kp * BATCH + bb) * 4) = o.v;
    };

    // ---- stage chunk 0 (burst) ----
    uint64_t lo[PPT], hi[PPT];
    #pragma unroll
    for (int r = 0; r < PPT; ++r) {
      const int u = r * NT + tid, k0 = (u >> 5) * 2, bb = (u & 31) * 4;
      lo[r] = ld8(k0, bb); hi[r] = ld8(k0 + 1, bb);
    }
    #pragma unroll
    for (int r = 0; r < PPT; ++r) park(buf0, r * NT + tid, lo[r], hi[r]);
    __syncthreads();

    for (int ch = 0; ch < NCH; ++ch) {
      unsigned* cur = (ch & 1) ? buf1 : buf0;
      unsigned* nxt = (ch & 1) ? buf0 : buf1;
      const int kb = ch * CK;
      const bool more = (ch + 1 < NCH);

      if (more) {
        const int kbn = kb + CK;
        #pragma unroll
        for (int r = 0; r < PPT; ++r) {
          const int u = r * NT + tid, k0 = kbn + (u >> 5) * 2, bb = (u & 31) * 4;
          lo[r] = ld8(k0, bb); hi[r] = ld8(k0 + 1, bb);
        }
      }

      const int kmax = (K - kb < CK) ? (K - kb) : CK;
      const int KPC  = kmax / 2;
      const int kbp  = kb / 2;
      #pragma unroll 4
      for (int kp = 0; kp < KPC; ++kp) {
        h8v w = *(const h8v*)(wlds + ((size_t)(kbp + kp) * NJ + jj) * 8);
        h2v w0 = {w[0], w[1]}, w1 = {w[2], w[3]}, w2 = {w[4], w[5]}, w3 = {w[6], w[7]};
        if constexpr (MB == 1) {
          union { unsigned u; h2v h; } hp; hp.u = cur[kp * BATCH + b0];
          a[0].x = dot2(w0, hp.h, a[0].x); a[0].y = dot2(w1, hp.h, a[0].y);
          a[0].z = dot2(w2, hp.h, a[0].z); a[0].w = dot2(w3, hp.h, a[0].w);
        } else if constexpr (MB == 2) {
          union { uint2 u; h2v h[2]; } hp; hp.u = *(const uint2*)(cur + kp * BATCH + b0);
          a[0].x = dot2(w0, hp.h[0], a[0].x); a[0].y = dot2(w1, hp.h[0], a[0].y);
          a[0].z = dot2(w2, hp.h[0], a[0].z); a[0].w = dot2(w3, hp.h[0], a[0].w);
          a[1].x = dot2(w0, hp.h[1], a[1].x); a[1].y = dot2(w1, hp.h[1], a[1].y);
          a[1].z = dot2(w2, hp.h[1], a[1].z); a[1].w = dot2(w3, hp.h[1], a[1].w);
        } else {
          union { uint4 u; h2v h[4]; } hp; hp.u = *(const uint4*)(cur + kp * BATCH + b0);
          #pragma unroll
          for (int m = 0; m < 4; ++m) {
            a[m].x = dot2(w0, hp.h[m], a[m].x); a[m].y = dot2(w1, hp.h[m], a[m].y);
            a[m].z = dot2(w2, hp.h[m], a[m].z); a[m].w = dot2(w3, hp.h[m], a[m].w);
          }
        }
      }

      if (more) {
        #pragma unroll
        for (int r = 0; r < PPT; ++r) park(nxt, r * NT + tid, lo[r], hi[r]);
      }
      __syncthreads();
    }

    // ---- epilogue: gates, state, sc1 f16 h store into slot t ----
    f16* dst = ownH + (size_t)(t & (RING - 1)) * H * BATCH + (size_t)j * BATCH + b0;
    float hv[MB];
    #pragma unroll
    for (int m = 0; m < MB; ++m) {
      float ig = sigm(a[m].x + bias.x);
      float fg = sigm(a[m].y + bias.y);
      float gg = tanhf(a[m].z + bias.z);
      float og = sigm(a[m].w + bias.w);
      c[m] = fg * c[m] + ig * gg;
      hv[m] = og * tanhf(c[m]);
    }
    if constexpr (MB == 4) {
      union { f16 h[4]; uint64_t u; } o;
      o.h[0] = (f16)hv[0]; o.h[1] = (f16)hv[1]; o.h[2] = (f16)hv[2]; o.h[3] = (f16)hv[3];
      c_store8(dst, o.u);
    } else if constexpr (MB == 2) {
      union { f16 h[2]; unsigned u; } o;
      o.h[0] = (f16)hv[0]; o.h[1] = (f16)hv[1];
      c_store4(dst, o.u);
    } else {
      union { f16 h; unsigned short u; } o;
      o.h = (f16)hv[0];
      c_store2(dst, o.u);
    }

    asm volatile("s_waitcnt vmcnt(0)" ::: "memory");
    __syncthreads();
    if (tid == 0) u_store(&U[bid], (unsigned)(t + 1));
  }
}

// ---------------- dense head ----------------
__device__ void dense_stage(const float* in, float* outb,
                            const float* __restrict__ w, const float* __restrict__ bias,
                            int din, int dout, bool relu) {
  for (int jc = threadIdx.x; jc < dout; jc += NT) {
    float s = bias[jc];
    for (int d = 0; d < din; ++d) s += in[d] * w[(size_t)d * dout + jc];
    outb[jc] = relu ? fmaxf(s, 0.f) : s;
  }
  __syncthreads();
}

constexpr size_t cmax(size_t a, size_t b) { return a > b ? a : b; }

// ---------------- fused cooperative kernel ----------------
template<int TB1, int TB2, int TB3, int TB4, int RING, int CK>
__global__ __launch_bounds__(NT, 2) void fused_kernel(KParams p) {
  constexpr int TNB = TB1 + TB2 + TB3 + TB4;
  constexpr int NGRID = TNB + 4;
  constexpr int TRB2 = TB1, TRB3 = TB1 + TB2, TRB4 = TB1 + TB2 + TB3;
  constexpr int NJ1 = 640 / TB1, NJ2 = 400 / TB2, NJ3 = 256 / TB3, NJ4 = 256 / TB4;
  using L = WS<RING>;
  constexpr size_t DBUF = (size_t)CK * 256 * 2;    // two pair buffers
  constexpr size_t SM = cmax(cmax((704/2)*NJ1*16 + DBUF, (1040/2)*NJ2*16 + DBUF),
                       cmax(cmax((656/2)*NJ3*16 + DBUF, (512/2)*NJ4*16 + DBUF), (size_t)16640));

  cg::grid_group grid = cg::this_grid();
  __shared__ __attribute__((aligned(16))) char smem[SM];

  char* ws = p.ws;
  unsigned* U = (unsigned*)(ws + L::BAR);
  const int tid  = threadIdx.x;
  const int bid  = blockIdx.x;
  const int gtid = bid * NT + tid;
  const int gstr = NGRID * NT;

  // ---- phase 0a: prepack weights (f16, kpair layout) ----
  prepack_layer(p.k1, p.r1, (f16*)(ws + L::PK1), 64,  640, NJ1, TB1, gtid, gstr);
  prepack_layer(p.k2, p.r2, (f16*)(ws + L::PK2), 640, 400, NJ2, TB2, gtid, gstr);
  prepack_layer(p.k3, p.r3, (f16*)(ws + L::PK3), 400, 256, NJ3, TB3, gtid, gstr);
  prepack_layer(p.k4, p.r4, (f16*)(ws + L::PK4), 256, 256, NJ4, TB4, gtid, gstr);
  // ---- phase 0b: transpose x [128][512][64] f32 -> xT [512][64][128] f16 ----
  {
    float* tile = (float*)smem;          // [32][129] f32 = 16,512 B
    f16* xT = (f16*)(ws + L::XT);
    for (int t = bid; t < TSTEPS; t += NGRID) {
      #pragma unroll
      for (int pass = 0; pass < 2; ++pass) {
        const int d0 = pass * 32;
        const int b = tid >> 1, half = tid & 1;
        const float* src = p.x + ((size_t)b * TSTEPS + t) * 64 + d0 + half * 16;
        float4 v[4];
        #pragma unroll
        for (int q = 0; q < 4; ++q) v[q] = *(const float4*)(src + 4 * q);
        __syncthreads();
        #pragma unroll
        for (int q = 0; q < 4; ++q) {
          tile[(half * 16 + 4 * q + 0) * 129 + b] = v[q].x;
          tile[(half * 16 + 4 * q + 1) * 129 + b] = v[q].y;
          tile[(half * 16 + 4 * q + 2) * 129 + b] = v[q].z;
          tile[(half * 16 + 4 * q + 3) * 129 + b] = v[q].w;
        }
        __syncthreads();
        const int r = tid >> 3, seg = tid & 7;
        f16* dst = xT + ((size_t)t * 64 + d0 + r) * BATCH + seg * 16;
        h8v o0, o1;
        #pragma unroll
        for (int i = 0; i < 8; ++i) {
          o0[i] = (f16)tile[r * 129 + seg * 16 + i];
          o1[i] = (f16)tile[r * 129 + seg * 16 + 8 + i];
        }
        *(h8v*)dst = o0;
        *(h8v*)(dst + 8) = o1;
      }
    }
  }

  grid.sync();   // publish packs/xT device-wide

  // ---- phase 1: dataflow-pipelined 4-layer LSTM scan ----
  if (bid >= TNB) {
    const int l = bid - TNB;
    if (l == 0)      control_role<TB1>(U, 0,    0);
    else if (l == 1) control_role<TB2>(U, TRB2, 1);
    else if (l == 2) control_role<TB3>(U, TRB3, 2);
    else             control_role<TB4>(U, TRB4, 3);
  } else if (bid < TRB2) {
    lstm_role< 64, 640, NJ1, 0, true , RING, CK>(bid,        bid, (const f16*)(ws + L::XT),
                                       (f16*)(ws + L::H1), (const f16*)(ws + L::PK1), p.b1, smem, U);
  } else if (bid < TRB3) {
    lstm_role<640, 400, NJ2, 1, false, RING, CK>(bid - TRB2, bid, (const f16*)(ws + L::H1),
                                       (f16*)(ws + L::H2), (const f16*)(ws + L::PK2), p.b2, smem, U);
  } else if (bid < TRB4) {
    lstm_role<400, 256, NJ3, 2, false, RING, CK>(bid - TRB3, bid, (const f16*)(ws + L::H2),
                                       (f16*)(ws + L::H3), (const f16*)(ws + L::PK3), p.b3, smem, U);
  } else {
    lstm_role<256, 256, NJ4, 3, false, RING, CK>(bid - TRB4, bid, (const f16*)(ws + L::H3),
                                       (f16*)(ws + L::H4), (const f16*)(ws + L::PK4), p.b4, smem, U);
  }

  // ---- phase 2: dense head ----
  if (bid < BATCH) {
    if (tid == 0) {
      const unsigned* relp = &U[512 + (bid & 15) * 64];
      while ((int)u_load(&relp[3]) < TSTEPS) {}
    }
    __syncthreads();
    const int b = bid;
    float* A = (float*)smem;
    float* B = (float*)smem + 512;
    const f16* h4 = (const f16*)(ws + L::H4)
                  + (size_t)((TSTEPS - 1) & (RING - 1)) * 256 * BATCH;
    for (int d = tid; d < 256; d += NT) {
      union { unsigned short u; f16 h; } cc;
      cc.u = c_load2(h4 + (size_t)d * BATCH + b);
      A[d] = (float)cc.h;
    }
    __syncthreads();
    dense_stage(A, B, p.wd1, p.bd1, 256, 512, true);
    dense_stage(B, A, p.wd2, p.bd2, 512, 256, true);
    dense_stage(A, B, p.wd3, p.bd3, 256, 128, true);
    dense_stage(B, A, p.wd4, p.bd4, 128, 64,  true);
    dense_stage(A, B, p.wd5, p.bd5, 64,  16,  true);
    dense_stage(B, A, p.wd6, p.bd6, 16,  3,   false);
    if (tid == 0) {
      float z0 = A[0], z1 = A[1], z2 = A[2];
      float m  = fmaxf(fmaxf(z0, z1), z2);
      float e0 = expf(z0 - m), e1 = expf(z1 - m), e2 = expf(z2 - m);
      float s  = e0 + e1 + e2;
      p.out[b * 3 + 0] = e0 / s;
      p.out[b * 3 + 1] = e1 / s;
      p.out[b * 3 + 2] = e2 / s;
    }
  }
}

// ---------------- launch: ws-size + occupancy + error-checked selection ----------------
extern "C" void kernel_launch(void* const* d_in, const int* in_sizes, int n_in,
                              void* d_out, int out_size, void* d_ws, size_t ws_size,
                              hipStream_t stream) {
  KParams prm;
  prm.x  = (const float*)d_in[0];
  prm.k1 = (const float*)d_in[1];  prm.r1 = (const float*)d_in[2];  prm.b1 = (const float*)d_in[3];
  prm.k2 = (const float*)d_in[4];  prm.r2 = (const float*)d_in[5];  prm.b2 = (const float*)d_in[6];
  prm.k3 = (const float*)d_in[7];  prm.r3 = (const float*)d_in[8];  prm.b3 = (const float*)d_in[9];
  prm.k4 = (const float*)d_in[10]; prm.r4 = (const float*)d_in[11]; prm.b4 = (const float*)d_in[12];
  prm.wd1 = (const float*)d_in[13]; prm.bd1 = (const float*)d_in[14];
  prm.wd2 = (const float*)d_in[15]; prm.bd2 = (const float*)d_in[16];
  prm.wd3 = (const float*)d_in[17]; prm.bd3 = (const float*)d_in[18];
  prm.wd4 = (const float*)d_in[19]; prm.bd4 = (const float*)d_in[20];
  prm.wd5 = (const float*)d_in[21]; prm.bd5 = (const float*)d_in[22];
  prm.wd6 = (const float*)d_in[23]; prm.bd6 = (const float*)d_in[24];
  prm.out = (float*)d_out;
  prm.ws  = (char*)d_ws;

  const bool big = ws_size >= WS<TSTEPS>::END;
  const size_t bar_off = big ? WS<TSTEPS>::BAR : WS<4>::BAR;
  hipMemsetAsync((char*)d_ws + bar_off, 0, 8192, stream);

  int maxb = 0;
  hipOccupancyMaxActiveBlocksPerMultiprocessor(
      &maxb, big ? (const void*)fused_kernel<160, 200, 64, 64, TSTEPS, 48>
                 : (const void*)fused_kernel<160, 200, 64, 64, 4, 48>, NT, 0);

  void* args[] = { &prm };
  hipError_t e = hipErrorUnknown;
  if (maxb >= 2) {
    e = big ? hipLaunchCooperativeKernel((void*)fused_kernel<160, 200, 64, 64, TSTEPS, 48>,
                                         dim3(492), dim3(NT), args, 0, stream)
            : hipLaunchCooperativeKernel((void*)fused_kernel<160, 200, 64, 64, 4, 48>,
                                         dim3(492), dim3(NT), args, 0, stream);
  }
  if (e != hipSuccess) {
    if (big) hipLaunchCooperativeKernel((void*)fused_kernel<80, 100, 32, 32, TSTEPS, 32>,
                                        dim3(248), dim3(NT), args, 0, stream);
    else     hipLaunchCooperativeKernel((void*)fused_kernel<80, 100, 32, 32, 4, 32>,
                                        dim3(248), dim3(NT), args, 0, stream);
  }
}